// Round 6
// baseline (684.151 us; speedup 1.0000x reference)
//
#include <hip/hip_runtime.h>
#include <hip/hip_bf16.h>
#include <cstdint>

#define NBLK 1024      // graphs
#define NPG  128       // nodes per graph
#define EPG  512       // edges per graph
#define DD   64        // feature dim
#define NSTEP 5        // MAX_STEPS + 1
#define ETOT (NBLK*EPG)
#define NEGF (-1e30f)
#define WAVES 4
#define MAXDEG 32      // P(Poisson(4) > 32) ~ 1e-19 per node; safe cap

// output element offsets (fp32 elements)
#define OA  0                       // actions_seq [B,S]
#define OLS 5120                    // log_pf sum [B]
#define OPF 6144                    // log_pf_steps [B,S]
#define OPB 11264                   // log_pb_steps [B,S]
#define OU  16384                   // used [E]
#define OSN 540672                  // stop nodes [B]
#define OST 541696                  // steps [B]

struct KeysArg {
  uint32_t ke0[NSTEP], ke1[NSTEP];  // edge-gumbel keys per step
  uint32_t ks0[NSTEP], ks1[NSTEP];  // stop-gumbel keys per step
};

__host__ __device__ inline uint32_t rotl32(uint32_t x, int r){ return (x<<r)|(x>>(32-r)); }

// JAX threefry2x32 (20 rounds), bit-exact
__host__ __device__ inline void tf2x32(uint32_t k0, uint32_t k1, uint32_t& x0, uint32_t& x1){
  uint32_t k2 = k0 ^ k1 ^ 0x1BD11BDAu;
  x0 += k0; x1 += k1;
  x0+=x1; x1=rotl32(x1,13); x1^=x0;
  x0+=x1; x1=rotl32(x1,15); x1^=x0;
  x0+=x1; x1=rotl32(x1,26); x1^=x0;
  x0+=x1; x1=rotl32(x1, 6); x1^=x0;
  x0+=k1; x1+=k2+1u;
  x0+=x1; x1=rotl32(x1,17); x1^=x0;
  x0+=x1; x1=rotl32(x1,29); x1^=x0;
  x0+=x1; x1=rotl32(x1,16); x1^=x0;
  x0+=x1; x1=rotl32(x1,24); x1^=x0;
  x0+=k2; x1+=k0+2u;
  x0+=x1; x1=rotl32(x1,13); x1^=x0;
  x0+=x1; x1=rotl32(x1,15); x1^=x0;
  x0+=x1; x1=rotl32(x1,26); x1^=x0;
  x0+=x1; x1=rotl32(x1, 6); x1^=x0;
  x0+=k0; x1+=k1+3u;
  x0+=x1; x1=rotl32(x1,17); x1^=x0;
  x0+=x1; x1=rotl32(x1,29); x1^=x0;
  x0+=x1; x1=rotl32(x1,16); x1^=x0;
  x0+=x1; x1=rotl32(x1,24); x1^=x0;
  x0+=k1; x1+=k2+4u;
  x0+=x1; x1=rotl32(x1,13); x1^=x0;
  x0+=x1; x1=rotl32(x1,15); x1^=x0;
  x0+=x1; x1=rotl32(x1,26); x1^=x0;
  x0+=x1; x1=rotl32(x1, 6); x1^=x0;
  x0+=k2; x1+=k0+5u;
}

// JAX uniform(minval=tiny, maxval=1) -> gumbel, bit-faithful
__device__ inline float gumbel_from_bits(uint32_t bits){
  float f = __uint_as_float((bits>>9) | 0x3f800000u) - 1.0f;   // [0,1)
  const float tiny = 1.17549435e-38f;
  float u = fmaxf(tiny, f * (1.0f - tiny) + tiny);
  return -logf(-logf(u));
}

// JAX partitionable threefry: bits[idx] = xor-fold of block at counter (0, idx)
__device__ inline float gumbel_part(uint32_t k0, uint32_t k1, uint32_t idx){
  uint32_t x0 = 0u, x1 = idx;
  tf2x32(k0, k1, x0, x1);
  return gumbel_from_bits(x0 ^ x1);
}

// full-wave (64-lane) sum; identical value on all lanes, deterministic order
__device__ inline float wsum(float x){
  #pragma unroll
  for (int off = 32; off; off >>= 1) x += __shfl_xor(x, off, 64);
  return x;
}

// broadcast lane i of v via v_readlane (VALU pipe, literal lane after unroll)
// — NOT ds_bpermute (LDS pipe). All callers are wave-uniform, all 64 lanes active.
__device__ __forceinline__ float rdlane(float v, int i){
  return __int_as_float(__builtin_amdgcn_readlane(__float_as_int(v), i));
}

// column matvec: sum_i broadcast(v,i) * W[i*DD+lane]; 4 accs, FULL unroll
// (literal readlane indices, 64 loads in flight). Acc order == round-4/5.
__device__ __forceinline__ float matvec_col(const float* __restrict__ W, float v, int lane){
  float a0=0.f, a1=0.f, a2=0.f, a3=0.f;
  #pragma unroll
  for (int i = 0; i < DD; i += 4){
    a0 = fmaf(rdlane(v, i  ), W[(i  )*DD+lane], a0);
    a1 = fmaf(rdlane(v, i+1), W[(i+1)*DD+lane], a1);
    a2 = fmaf(rdlane(v, i+2), W[(i+2)*DD+lane], a2);
    a3 = fmaf(rdlane(v, i+3), W[(i+3)*DD+lane], a3);
  }
  return (a0+a1)+(a2+a3);
}

// 4-candidate batched matvec: each W row read ONCE, 4 outputs.
// Per-candidate accumulation order bit-identical to matvec_col.
__device__ __forceinline__ void matvec4(const float* __restrict__ W,
                                        float v0, float v1, float v2, float v3,
                                        int lane, float o[4]){
  float acc[4][4] = {{0,0,0,0},{0,0,0,0},{0,0,0,0},{0,0,0,0}};
  #pragma unroll
  for (int i = 0; i < DD; i += 4){
    #pragma unroll
    for (int t = 0; t < 4; t++){
      float w  = W[(i+t)*DD+lane];
      acc[0][t] = fmaf(rdlane(v0, i+t), w, acc[0][t]);
      acc[1][t] = fmaf(rdlane(v1, i+t), w, acc[1][t]);
      acc[2][t] = fmaf(rdlane(v2, i+t), w, acc[2][t]);
      acc[3][t] = fmaf(rdlane(v3, i+t), w, acc[3][t]);
    }
  }
  #pragma unroll
  for (int c = 0; c < 4; c++)
    o[c] = (acc[c][0]+acc[c][1])+(acc[c][2]+acc[c][3]);
}

__global__ void __launch_bounds__(256)
gfn_fused(const float* __restrict__ node_tokens,
          const float* __restrict__ edge_emb,
          const float* __restrict__ Wf1, const float* __restrict__ Wnf, const float* __restrict__ Wf2,
          const float* __restrict__ bf,  const float* __restrict__ wf,
          const float* __restrict__ Wb1, const float* __restrict__ Wnb, const float* __restrict__ Wb2,
          const float* __restrict__ bb,  const float* __restrict__ wb,
          const float* __restrict__ w_stop, const float* __restrict__ b_stop,
          const float* __restrict__ Ws,  const float* __restrict__ Wu, const float* __restrict__ bu,
          const int* __restrict__ e_src, const int* __restrict__ e_dst,
          float* __restrict__ out, KeysArg keys)
{
  const int g    = blockIdx.x;
  const int tid  = threadIdx.x;
  const int lane = tid & 63;
  const int wave = tid >> 6;
  const int ebase = g * EPG;

  __shared__ uint8_t  srcL[EPG], dstL[EPG];       // local endpoints (0..127)
  __shared__ uint16_t listO[EPG], listI[EPG];     // CSR lists (ascending edge id)
  __shared__ int cntO[NPG], cntI[NPG], begO[NPG], begI[NPG];
  __shared__ uint8_t usedL[EPG];
  __shared__ float st[DD];                        // state vector
  __shared__ float a_sh[MAXDEG][DD];              // per-candidate pre-activation
  __shared__ float u_sh[DD], nt_sh[DD];           // fwd shared vectors
  __shared__ float ub_sh[DD], ntb_sh[DD];         // bwd shared vectors
  __shared__ float acs_sh[DD], acr_sh[DD];        // state-update partials
  __shared__ float xc[MAXDEG], gm[MAXDEG];        // scores, gumbels
  __shared__ float sl_sh, gs_sh, sh_xbb;

  // ---- load edges, init ----
  for (int j = tid; j < EPG; j += 256){
    srcL[j] = (uint8_t)(e_src[ebase+j] - g*NPG);
    dstL[j] = (uint8_t)(e_dst[ebase+j] - g*NPG);
    usedL[j] = 0;
  }
  for (int n = tid; n < NPG; n += 256){ cntO[n]=0; cntI[n]=0; }
  if (tid < DD) st[tid] = 0.f;
  __syncthreads();

  // ---- count degrees ----
  for (int j = tid; j < EPG; j += 256){
    atomicAdd(&cntO[srcL[j]], 1);
    atomicAdd(&cntI[dstL[j]], 1);
  }
  __syncthreads();

  // ---- exclusive prefix sum via wave-0 shfl scan (2 nodes/lane) ----
  if (wave == 0){
    int n0 = lane*2, n1 = n0+1;
    int c0O=cntO[n0], c1O=cntO[n1], sO=c0O+c1O;
    int c0I=cntI[n0], c1I=cntI[n1], sI=c0I+c1I;
    int xO=sO, xI=sI;
    #pragma unroll
    for (int off=1; off<64; off<<=1){
      int tO=__shfl_up(xO,off,64), tI=__shfl_up(xI,off,64);
      if (lane>=off){ xO+=tO; xI+=tI; }
    }
    begO[n0]=xO-sO; begO[n1]=xO-c1O;
    begI[n0]=xI-sI; begI[n1]=xI-c1I;
  }
  __syncthreads();
  for (int n = tid; n < NPG; n += 256){ cntO[n]=0; cntI[n]=0; }
  __syncthreads();

  // ---- phased fill: ascending edge-id order, deterministic ----
  for (int ph = 0; ph < WAVES; ph++){
    if (wave == ph){
      #pragma unroll
      for (int h = 0; h < 2; h++){
        int j = ph*128 + h*64 + lane;
        int sL = srcL[j]; int p = atomicAdd(&cntO[sL],1); listO[begO[sL]+p] = (uint16_t)j;
        int dL = dstL[j]; int q = atomicAdd(&cntI[dL],1); listI[begI[dL]+q] = (uint16_t)j;
      }
    }
    __syncthreads();
  }

  // per-lane copies of small vectors
  const float bf_l = bf[lane], wf_l = wf[lane];
  const float bb_l = bb[lane], wb_l = wb[lane];
  const float wst_l = w_stop[lane];
  const float bstop = b_stop[0];

  // block-uniform rollout state (replicated per thread)
  bool done = false;
  int stepsC = 0;
  int stopn = -1;
  int activeL = 0;
  float lpf_sum = 0.f;

  for (int s = 0; s < NSTEP; s++){
    float act_out = -1.f, lpf_out = 0.f, lpb_out = 0.f;
    if (!done){
      const int bO = begO[activeL];
      const int dOc = min(cntO[activeL], MAXDEG);
      float st_v = st[lane];

      // ---- P1: specialized concurrent passes ----
      if (wave == 0){                       // u = Wf2^T st
        u_sh[lane] = matvec_col(Wf2, st_v, lane);
      } else if (wave == 1){                // nt = Wnf^T node_tokens[active]
        float ntv = node_tokens[(size_t)(g*NPG + activeL)*DD + lane];
        nt_sh[lane] = matvec_col(Wnf, ntv, lane);
      } else if (wave == 2){                // fwd candidates: a_k = Wf1^T e_k (batched)
        for (int base = 0; base < dOc; base += 4){
          float v[4];
          #pragma unroll
          for (int t = 0; t < 4; t++){
            int k = base + t;
            int el = listO[bO + min(k, dOc-1)];
            v[t] = edge_emb[(size_t)(ebase+el)*DD + lane];
          }
          float o[4];
          matvec4(Wf1, v[0], v[1], v[2], v[3], lane, o);
          #pragma unroll
          for (int t = 0; t < 4; t++){
            int k = base + t;
            if (k < dOc) a_sh[k][lane] = o[t];
          }
        }
      } else {                              // stop logit + all gumbels (lane-parallel)
        float sl = wsum(st_v * wst_l) + bstop;
        if (lane == 0) sl_sh = sl;
        if (lane < dOc){
          int el = listO[bO + lane];
          gm[lane] = gumbel_part(keys.ke0[s], keys.ke1[s], (uint32_t)(ebase+el));
        }
        if (lane == 63) gs_sh = gumbel_part(keys.ks0[s], keys.ks1[s], (uint32_t)g);
      }
      __syncthreads();

      // ---- P2: score epilogue (round-4 add order: ((a+nt)+bf)+u) ----
      for (int k = wave; k < dOc; k += WAVES){
        int el = listO[bO + k];
        float x = NEGF;
        if (!usedL[el]){
          float h = fmaxf(a_sh[k][lane] + nt_sh[lane] + bf_l + u_sh[lane], 0.f);
          x = wsum(h * wf_l);
        }
        if (lane == 0) xc[k] = x;
      }
      __syncthreads();

      // ---- P3: combine + selection (redundant on all threads, block-uniform) ----
      float sl = sl_sh;
      float m1 = NEGF; int nvalid = 0;
      for (int k=0;k<dOc;k++){ float xk=xc[k]; if (xk!=NEGF){ m1=fmaxf(m1,xk); nvalid++; } }
      float ssum = 0.f;
      for (int k=0;k<dOc;k++){ float xk=xc[k]; if (xk!=NEGF) ssum += expf(xk - m1); }
      const bool has_edge = nvalid > 0;
      float lse_e = m1 + logf(fmaxf(ssum, 1e-30f));
      const bool allow_stop = (stepsC < 4);
      float stop_t = allow_stop ? sl : NEGF;
      float amx = fmaxf(lse_e, stop_t);
      float Z = amx + log1pf(expf(-fabsf(lse_e - stop_t)));

      float mbest = NEGF; int elbest = -1; float xbest = 0.f;
      for (int k=0;k<dOc;k++){
        float xk = xc[k];
        if (xk == NEGF) continue;
        float se = (xk - Z) + gm[k];
        if (se > mbest){ mbest = se; elbest = listO[bO+k]; xbest = xk; }
      }
      float ss = allow_stop ? (sl - Z) + gs_sh : NEGF;
      float mcmp = has_edge ? mbest : NEGF;
      const bool choose_stop = (ss > mcmp) || (!has_edge);
      float logp_stop = allow_stop ? (sl - Z) : 0.f;
      const bool take_edge = !choose_stop;

      act_out = choose_stop ? -1.f : (float)(ebase + elbest);
      lpf_out = choose_stop ? logp_stop : (xbest - Z);
      if (choose_stop && stopn < 0) stopn = activeL;

      // ---- P4: state update (w0: Ws^T st, w1: Wu^T rel, concurrent) ----
      if (take_edge){
        if (wave == 0){
          acs_sh[lane] = matvec_col(Ws, st_v, lane);
        } else if (wave == 1){
          float rv = edge_emb[(size_t)(ebase+elbest)*DD + lane];
          acr_sh[lane] = matvec_col(Wu, rv, lane);
        }
      }
      __syncthreads();
      if (take_edge){
        if (tid < DD) st[tid] = tanhf(acs_sh[tid] + acr_sh[tid] + bu[tid]);
        if (tid == 0) usedL[elbest] = 1;
        activeL = dstL[elbest];
        stepsC++;
      }
      __syncthreads();

      // ---- P5: backward passes (w0: Wb2^T st', w1: Wnb^T nt', w2: candidates) ----
      const int bI = begI[activeL];
      const int dIc = take_edge ? min(cntI[activeL], MAXDEG) : 0;
      if (take_edge){
        if (wave == 0){
          ub_sh[lane] = matvec_col(Wb2, st[lane], lane);
        } else if (wave == 1){
          float nbv = node_tokens[(size_t)(g*NPG + activeL)*DD + lane];
          ntb_sh[lane] = matvec_col(Wnb, nbv, lane);
        } else if (wave == 2){
          for (int base = 0; base < dIc; base += 4){
            float v[4];
            #pragma unroll
            for (int t = 0; t < 4; t++){
              int k = base + t;
              int el = listI[bI + min(k, dIc-1)];
              v[t] = edge_emb[(size_t)(ebase+el)*DD + lane];
            }
            float o[4];
            matvec4(Wb1, v[0], v[1], v[2], v[3], lane, o);
            #pragma unroll
            for (int t = 0; t < 4; t++){
              int k = base + t;
              if (k < dIc) a_sh[k][lane] = o[t];
            }
          }
        }
      }
      __syncthreads();

      // ---- P6: backward score epilogue + combine ----
      if (take_edge){
        for (int k = wave; k < dIc; k += WAVES){
          int el = listI[bI + k];
          float h = fmaxf(a_sh[k][lane] + ntb_sh[lane] + bb_l + ub_sh[lane], 0.f);
          float xb = wsum(h * wb_l);
          if (lane == 0){ xc[k] = xb; if (el == elbest) sh_xbb = xb; }
        }
      }
      __syncthreads();
      if (take_edge){
        float m2 = NEGF;
        for (int k=0;k<dIc;k++) m2 = fmaxf(m2, xc[k]);
        float s2 = 0.f;
        for (int k=0;k<dIc;k++) s2 += expf(xc[k] - m2);
        float lse_b = m2 + logf(fmaxf(s2, 1e-30f));
        lpb_out = sh_xbb - lse_b;
      }
      done = done || choose_stop;
      __syncthreads();
    }

    if (tid == 0){
      out[OA  + g*NSTEP + s] = act_out;
      out[OPF + g*NSTEP + s] = lpf_out;
      out[OPB + g*NSTEP + s] = lpb_out;
    }
    lpf_sum += lpf_out;
  }

  // ---- finalize ----
  if (tid == 0){
    out[OLS + g] = lpf_sum;
    int sn = (stopn < 0) ? activeL : stopn;
    out[OSN + g] = (float)sn;
    out[OST + g] = (float)stepsC;
  }
  for (int j = tid; j < EPG; j += 256)
    out[OU + ebase + j] = usedL[j] ? 1.0f : 0.0f;
}

extern "C" void kernel_launch(void* const* d_in, const int* in_sizes, int n_in,
                              void* d_out, int out_size, void* d_ws, size_t ws_size,
                              hipStream_t stream)
{
  (void)in_sizes; (void)n_in; (void)out_size; (void)d_ws; (void)ws_size;

  // JAX key schedule, threefry_partitionable (default since jax 0.4.36):
  // key(42)=(0,42); keys[s]=tf(key,(0,s)); ke=tf(keys[s],(0,0)), ksn=tf(keys[s],(0,1))
  KeysArg K;
  for (uint32_t s = 0; s < NSTEP; s++){
    uint32_t a = 0u, b = s;
    tf2x32(0u, 42u, a, b);
    uint32_t e0 = 0u, e1 = 0u;
    tf2x32(a, b, e0, e1);
    uint32_t s0 = 0u, s1 = 1u;
    tf2x32(a, b, s0, s1);
    K.ke0[s] = e0; K.ke1[s] = e1;
    K.ks0[s] = s0; K.ks1[s] = s1;
  }

  const int* eidx = (const int*)d_in[17];
  gfn_fused<<<dim3(NBLK), dim3(256), 0, stream>>>(
      (const float*)d_in[0],  (const float*)d_in[1],
      (const float*)d_in[2],  (const float*)d_in[3],  (const float*)d_in[4],
      (const float*)d_in[5],  (const float*)d_in[6],
      (const float*)d_in[7],  (const float*)d_in[8],  (const float*)d_in[9],
      (const float*)d_in[10], (const float*)d_in[11],
      (const float*)d_in[12], (const float*)d_in[13],
      (const float*)d_in[14], (const float*)d_in[15], (const float*)d_in[16],
      eidx, eidx + ETOT,
      (float*)d_out, K);
}

// Round 7
// 91.906 us; speedup vs baseline: 7.4440x; 7.4440x over previous
//
#include <hip/hip_runtime.h>
#include <hip/hip_bf16.h>
#include <cstdint>

#define NBLK 1024      // graphs
#define NPG  128       // nodes per graph
#define EPG  512       // edges per graph
#define DD   64        // feature dim
#define NSTEP 5        // MAX_STEPS + 1
#define ETOT (NBLK*EPG)
#define NEGF (-1e30f)
#define WAVES 4
#define MAXDEG 32      // P(Poisson(4) > 32) ~ 1e-19 per node; safe cap

// output element offsets (fp32 elements)
#define OA  0                       // actions_seq [B,S]
#define OLS 5120                    // log_pf sum [B]
#define OPF 6144                    // log_pf_steps [B,S]
#define OPB 11264                   // log_pb_steps [B,S]
#define OU  16384                   // used [E]
#define OSN 540672                  // stop nodes [B]
#define OST 541696                  // steps [B]

struct KeysArg {
  uint32_t ke0[NSTEP], ke1[NSTEP];  // edge-gumbel keys per step
  uint32_t ks0[NSTEP], ks1[NSTEP];  // stop-gumbel keys per step
};

__host__ __device__ inline uint32_t rotl32(uint32_t x, int r){ return (x<<r)|(x>>(32-r)); }

// JAX threefry2x32 (20 rounds), bit-exact
__host__ __device__ inline void tf2x32(uint32_t k0, uint32_t k1, uint32_t& x0, uint32_t& x1){
  uint32_t k2 = k0 ^ k1 ^ 0x1BD11BDAu;
  x0 += k0; x1 += k1;
  x0+=x1; x1=rotl32(x1,13); x1^=x0;
  x0+=x1; x1=rotl32(x1,15); x1^=x0;
  x0+=x1; x1=rotl32(x1,26); x1^=x0;
  x0+=x1; x1=rotl32(x1, 6); x1^=x0;
  x0+=k1; x1+=k2+1u;
  x0+=x1; x1=rotl32(x1,17); x1^=x0;
  x0+=x1; x1=rotl32(x1,29); x1^=x0;
  x0+=x1; x1=rotl32(x1,16); x1^=x0;
  x0+=x1; x1=rotl32(x1,24); x1^=x0;
  x0+=k2; x1+=k0+2u;
  x0+=x1; x1=rotl32(x1,13); x1^=x0;
  x0+=x1; x1=rotl32(x1,15); x1^=x0;
  x0+=x1; x1=rotl32(x1,26); x1^=x0;
  x0+=x1; x1=rotl32(x1, 6); x1^=x0;
  x0+=k0; x1+=k1+3u;
  x0+=x1; x1=rotl32(x1,17); x1^=x0;
  x0+=x1; x1=rotl32(x1,29); x1^=x0;
  x0+=x1; x1=rotl32(x1,16); x1^=x0;
  x0+=x1; x1=rotl32(x1,24); x1^=x0;
  x0+=k1; x1+=k2+4u;
  x0+=x1; x1=rotl32(x1,13); x1^=x0;
  x0+=x1; x1=rotl32(x1,15); x1^=x0;
  x0+=x1; x1=rotl32(x1,26); x1^=x0;
  x0+=x1; x1=rotl32(x1, 6); x1^=x0;
  x0+=k2; x1+=k0+5u;
}

// JAX uniform(minval=tiny, maxval=1) -> gumbel, bit-faithful
__device__ inline float gumbel_from_bits(uint32_t bits){
  float f = __uint_as_float((bits>>9) | 0x3f800000u) - 1.0f;   // [0,1)
  const float tiny = 1.17549435e-38f;
  float u = fmaxf(tiny, f * (1.0f - tiny) + tiny);
  return -logf(-logf(u));
}

// JAX partitionable threefry: bits[idx] = xor-fold of block at counter (0, idx)
__device__ inline float gumbel_part(uint32_t k0, uint32_t k1, uint32_t idx){
  uint32_t x0 = 0u, x1 = idx;
  tf2x32(k0, k1, x0, x1);
  return gumbel_from_bits(x0 ^ x1);
}

// full-wave (64-lane) sum; identical value on all lanes, deterministic order
__device__ inline float wsum(float x){
  #pragma unroll
  for (int off = 32; off; off >>= 1) x += __shfl_xor(x, off, 64);
  return x;
}

// broadcast lane i of v via v_readlane_b32 (VALU pipe, SGPR dest; lane index
// is wave-uniform so SGPR-indexed readlane is legal). NOT ds_bpermute.
__device__ __forceinline__ float rdlane(float v, int i){
  return __int_as_float(__builtin_amdgcn_readlane(__float_as_int(v), i));
}

// column matvec: sum_i broadcast(v,i) * W[i*DD+lane]; 4 accs, PARTIAL unroll
// (round-5 register pressure), readlane broadcasts. Acc order == rounds 4/5.
__device__ __forceinline__ float matvec_col(const float* __restrict__ W, float v, int lane){
  float a0=0.f, a1=0.f, a2=0.f, a3=0.f;
  #pragma unroll 4
  for (int i = 0; i < DD; i += 4){
    a0 = fmaf(rdlane(v, i  ), W[(i  )*DD+lane], a0);
    a1 = fmaf(rdlane(v, i+1), W[(i+1)*DD+lane], a1);
    a2 = fmaf(rdlane(v, i+2), W[(i+2)*DD+lane], a2);
    a3 = fmaf(rdlane(v, i+3), W[(i+3)*DD+lane], a3);
  }
  return (a0+a1)+(a2+a3);
}

// 4-candidate batched matvec: each W row read ONCE, 4 outputs.
// Partial unroll (round-5 pressure); per-candidate acc order == matvec_col.
__device__ __forceinline__ void matvec4(const float* __restrict__ W,
                                        float v0, float v1, float v2, float v3,
                                        int lane, float o[4]){
  float acc[4][4] = {{0,0,0,0},{0,0,0,0},{0,0,0,0},{0,0,0,0}};
  #pragma unroll 4
  for (int i = 0; i < DD; i += 4){
    #pragma unroll
    for (int t = 0; t < 4; t++){
      float w  = W[(i+t)*DD+lane];
      acc[0][t] = fmaf(rdlane(v0, i+t), w, acc[0][t]);
      acc[1][t] = fmaf(rdlane(v1, i+t), w, acc[1][t]);
      acc[2][t] = fmaf(rdlane(v2, i+t), w, acc[2][t]);
      acc[3][t] = fmaf(rdlane(v3, i+t), w, acc[3][t]);
    }
  }
  #pragma unroll
  for (int c = 0; c < 4; c++)
    o[c] = (acc[c][0]+acc[c][1])+(acc[c][2]+acc[c][3]);
}

__global__ void __launch_bounds__(256)
gfn_fused(const float* __restrict__ node_tokens,
          const float* __restrict__ edge_emb,
          const float* __restrict__ Wf1, const float* __restrict__ Wnf, const float* __restrict__ Wf2,
          const float* __restrict__ bf,  const float* __restrict__ wf,
          const float* __restrict__ Wb1, const float* __restrict__ Wnb, const float* __restrict__ Wb2,
          const float* __restrict__ bb,  const float* __restrict__ wb,
          const float* __restrict__ w_stop, const float* __restrict__ b_stop,
          const float* __restrict__ Ws,  const float* __restrict__ Wu, const float* __restrict__ bu,
          const int* __restrict__ e_src, const int* __restrict__ e_dst,
          float* __restrict__ out, KeysArg keys)
{
  const int g    = blockIdx.x;
  const int tid  = threadIdx.x;
  const int lane = tid & 63;
  const int wave = tid >> 6;
  const int ebase = g * EPG;

  __shared__ uint8_t  srcL[EPG], dstL[EPG];       // local endpoints (0..127)
  __shared__ uint16_t listO[EPG], listI[EPG];     // CSR lists (ascending edge id)
  __shared__ int cntO[NPG], cntI[NPG], begO[NPG], begI[NPG];
  __shared__ uint8_t usedL[EPG];
  __shared__ float st[DD];                        // state vector
  __shared__ float a_sh[MAXDEG][DD];              // per-candidate pre-activation
  __shared__ float u_sh[DD], nt_sh[DD];           // fwd shared vectors
  __shared__ float ub_sh[DD], ntb_sh[DD];         // bwd shared vectors
  __shared__ float acs_sh[DD], acr_sh[DD];        // state-update partials
  __shared__ float xc[MAXDEG], gm[MAXDEG];        // scores, gumbels
  __shared__ float sl_sh, gs_sh, sh_xbb;

  // ---- load edges, init ----
  for (int j = tid; j < EPG; j += 256){
    srcL[j] = (uint8_t)(e_src[ebase+j] - g*NPG);
    dstL[j] = (uint8_t)(e_dst[ebase+j] - g*NPG);
    usedL[j] = 0;
  }
  for (int n = tid; n < NPG; n += 256){ cntO[n]=0; cntI[n]=0; }
  if (tid < DD) st[tid] = 0.f;
  __syncthreads();

  // ---- count degrees ----
  for (int j = tid; j < EPG; j += 256){
    atomicAdd(&cntO[srcL[j]], 1);
    atomicAdd(&cntI[dstL[j]], 1);
  }
  __syncthreads();

  // ---- exclusive prefix sum via wave-0 shfl scan (2 nodes/lane) ----
  if (wave == 0){
    int n0 = lane*2, n1 = n0+1;
    int c0O=cntO[n0], c1O=cntO[n1], sO=c0O+c1O;
    int c0I=cntI[n0], c1I=cntI[n1], sI=c0I+c1I;
    int xO=sO, xI=sI;
    #pragma unroll
    for (int off=1; off<64; off<<=1){
      int tO=__shfl_up(xO,off,64), tI=__shfl_up(xI,off,64);
      if (lane>=off){ xO+=tO; xI+=tI; }
    }
    begO[n0]=xO-sO; begO[n1]=xO-c1O;
    begI[n0]=xI-sI; begI[n1]=xI-c1I;
  }
  __syncthreads();
  for (int n = tid; n < NPG; n += 256){ cntO[n]=0; cntI[n]=0; }
  __syncthreads();

  // ---- phased fill: ascending edge-id order, deterministic ----
  for (int ph = 0; ph < WAVES; ph++){
    if (wave == ph){
      #pragma unroll
      for (int h = 0; h < 2; h++){
        int j = ph*128 + h*64 + lane;
        int sL = srcL[j]; int p = atomicAdd(&cntO[sL],1); listO[begO[sL]+p] = (uint16_t)j;
        int dL = dstL[j]; int q = atomicAdd(&cntI[dL],1); listI[begI[dL]+q] = (uint16_t)j;
      }
    }
    __syncthreads();
  }

  // per-lane copies of small vectors
  const float bf_l = bf[lane], wf_l = wf[lane];
  const float bb_l = bb[lane], wb_l = wb[lane];
  const float wst_l = w_stop[lane];
  const float bstop = b_stop[0];

  // block-uniform rollout state (replicated per thread)
  bool done = false;
  int stepsC = 0;
  int stopn = -1;
  int activeL = 0;
  float lpf_sum = 0.f;

  for (int s = 0; s < NSTEP; s++){
    float act_out = -1.f, lpf_out = 0.f, lpb_out = 0.f;
    if (!done){
      const int bO = begO[activeL];
      const int dOc = min(cntO[activeL], MAXDEG);
      float st_v = st[lane];

      // ---- P1: specialized concurrent passes ----
      if (wave == 0){                       // u = Wf2^T st
        u_sh[lane] = matvec_col(Wf2, st_v, lane);
      } else if (wave == 1){                // nt = Wnf^T node_tokens[active]
        float ntv = node_tokens[(size_t)(g*NPG + activeL)*DD + lane];
        nt_sh[lane] = matvec_col(Wnf, ntv, lane);
      } else if (wave == 2){                // fwd candidates: a_k = Wf1^T e_k (batched)
        for (int base = 0; base < dOc; base += 4){
          float v[4];
          #pragma unroll
          for (int t = 0; t < 4; t++){
            int k = base + t;
            int el = listO[bO + min(k, dOc-1)];
            v[t] = edge_emb[(size_t)(ebase+el)*DD + lane];
          }
          float o[4];
          matvec4(Wf1, v[0], v[1], v[2], v[3], lane, o);
          #pragma unroll
          for (int t = 0; t < 4; t++){
            int k = base + t;
            if (k < dOc) a_sh[k][lane] = o[t];
          }
        }
      } else {                              // stop logit + all gumbels (lane-parallel)
        float sl = wsum(st_v * wst_l) + bstop;
        if (lane == 0) sl_sh = sl;
        if (lane < dOc){
          int el = listO[bO + lane];
          gm[lane] = gumbel_part(keys.ke0[s], keys.ke1[s], (uint32_t)(ebase+el));
        }
        if (lane == 63) gs_sh = gumbel_part(keys.ks0[s], keys.ks1[s], (uint32_t)g);
      }
      __syncthreads();

      // ---- P2: score epilogue (round-4 add order: ((a+nt)+bf)+u) ----
      for (int k = wave; k < dOc; k += WAVES){
        int el = listO[bO + k];
        float x = NEGF;
        if (!usedL[el]){
          float h = fmaxf(a_sh[k][lane] + nt_sh[lane] + bf_l + u_sh[lane], 0.f);
          x = wsum(h * wf_l);
        }
        if (lane == 0) xc[k] = x;
      }
      __syncthreads();

      // ---- P3: combine + selection (redundant on all threads, block-uniform) ----
      float sl = sl_sh;
      float m1 = NEGF; int nvalid = 0;
      for (int k=0;k<dOc;k++){ float xk=xc[k]; if (xk!=NEGF){ m1=fmaxf(m1,xk); nvalid++; } }
      float ssum = 0.f;
      for (int k=0;k<dOc;k++){ float xk=xc[k]; if (xk!=NEGF) ssum += expf(xk - m1); }
      const bool has_edge = nvalid > 0;
      float lse_e = m1 + logf(fmaxf(ssum, 1e-30f));
      const bool allow_stop = (stepsC < 4);
      float stop_t = allow_stop ? sl : NEGF;
      float amx = fmaxf(lse_e, stop_t);
      float Z = amx + log1pf(expf(-fabsf(lse_e - stop_t)));

      float mbest = NEGF; int elbest = -1; float xbest = 0.f;
      for (int k=0;k<dOc;k++){
        float xk = xc[k];
        if (xk == NEGF) continue;
        float se = (xk - Z) + gm[k];
        if (se > mbest){ mbest = se; elbest = listO[bO+k]; xbest = xk; }
      }
      float ss = allow_stop ? (sl - Z) + gs_sh : NEGF;
      float mcmp = has_edge ? mbest : NEGF;
      const bool choose_stop = (ss > mcmp) || (!has_edge);
      float logp_stop = allow_stop ? (sl - Z) : 0.f;
      const bool take_edge = !choose_stop;

      act_out = choose_stop ? -1.f : (float)(ebase + elbest);
      lpf_out = choose_stop ? logp_stop : (xbest - Z);
      if (choose_stop && stopn < 0) stopn = activeL;

      // ---- P4: state update (w0: Ws^T st, w1: Wu^T rel, concurrent) ----
      if (take_edge){
        if (wave == 0){
          acs_sh[lane] = matvec_col(Ws, st_v, lane);
        } else if (wave == 1){
          float rv = edge_emb[(size_t)(ebase+elbest)*DD + lane];
          acr_sh[lane] = matvec_col(Wu, rv, lane);
        }
      }
      __syncthreads();
      if (take_edge){
        if (tid < DD) st[tid] = tanhf(acs_sh[tid] + acr_sh[tid] + bu[tid]);
        if (tid == 0) usedL[elbest] = 1;
        activeL = dstL[elbest];
        stepsC++;
      }
      __syncthreads();

      // ---- P5: backward passes (w0: Wb2^T st', w1: Wnb^T nt', w2: candidates) ----
      const int bI = begI[activeL];
      const int dIc = take_edge ? min(cntI[activeL], MAXDEG) : 0;
      if (take_edge){
        if (wave == 0){
          ub_sh[lane] = matvec_col(Wb2, st[lane], lane);
        } else if (wave == 1){
          float nbv = node_tokens[(size_t)(g*NPG + activeL)*DD + lane];
          ntb_sh[lane] = matvec_col(Wnb, nbv, lane);
        } else if (wave == 2){
          for (int base = 0; base < dIc; base += 4){
            float v[4];
            #pragma unroll
            for (int t = 0; t < 4; t++){
              int k = base + t;
              int el = listI[bI + min(k, dIc-1)];
              v[t] = edge_emb[(size_t)(ebase+el)*DD + lane];
            }
            float o[4];
            matvec4(Wb1, v[0], v[1], v[2], v[3], lane, o);
            #pragma unroll
            for (int t = 0; t < 4; t++){
              int k = base + t;
              if (k < dIc) a_sh[k][lane] = o[t];
            }
          }
        }
      }
      __syncthreads();

      // ---- P6: backward score epilogue + combine ----
      if (take_edge){
        for (int k = wave; k < dIc; k += WAVES){
          int el = listI[bI + k];
          float h = fmaxf(a_sh[k][lane] + ntb_sh[lane] + bb_l + ub_sh[lane], 0.f);
          float xb = wsum(h * wb_l);
          if (lane == 0){ xc[k] = xb; if (el == elbest) sh_xbb = xb; }
        }
      }
      __syncthreads();
      if (take_edge){
        float m2 = NEGF;
        for (int k=0;k<dIc;k++) m2 = fmaxf(m2, xc[k]);
        float s2 = 0.f;
        for (int k=0;k<dIc;k++) s2 += expf(xc[k] - m2);
        float lse_b = m2 + logf(fmaxf(s2, 1e-30f));
        lpb_out = sh_xbb - lse_b;
      }
      done = done || choose_stop;
      __syncthreads();
    }

    if (tid == 0){
      out[OA  + g*NSTEP + s] = act_out;
      out[OPF + g*NSTEP + s] = lpf_out;
      out[OPB + g*NSTEP + s] = lpb_out;
    }
    lpf_sum += lpf_out;
  }

  // ---- finalize ----
  if (tid == 0){
    out[OLS + g] = lpf_sum;
    int sn = (stopn < 0) ? activeL : stopn;
    out[OSN + g] = (float)sn;
    out[OST + g] = (float)stepsC;
  }
  for (int j = tid; j < EPG; j += 256)
    out[OU + ebase + j] = usedL[j] ? 1.0f : 0.0f;
}

extern "C" void kernel_launch(void* const* d_in, const int* in_sizes, int n_in,
                              void* d_out, int out_size, void* d_ws, size_t ws_size,
                              hipStream_t stream)
{
  (void)in_sizes; (void)n_in; (void)out_size; (void)d_ws; (void)ws_size;

  // JAX key schedule, threefry_partitionable (default since jax 0.4.36):
  // key(42)=(0,42); keys[s]=tf(key,(0,s)); ke=tf(keys[s],(0,0)), ksn=tf(keys[s],(0,1))
  KeysArg K;
  for (uint32_t s = 0; s < NSTEP; s++){
    uint32_t a = 0u, b = s;
    tf2x32(0u, 42u, a, b);
    uint32_t e0 = 0u, e1 = 0u;
    tf2x32(a, b, e0, e1);
    uint32_t s0 = 0u, s1 = 1u;
    tf2x32(a, b, s0, s1);
    K.ke0[s] = e0; K.ke1[s] = e1;
    K.ks0[s] = s0; K.ks1[s] = s1;
  }

  const int* eidx = (const int*)d_in[17];
  gfn_fused<<<dim3(NBLK), dim3(256), 0, stream>>>(
      (const float*)d_in[0],  (const float*)d_in[1],
      (const float*)d_in[2],  (const float*)d_in[3],  (const float*)d_in[4],
      (const float*)d_in[5],  (const float*)d_in[6],
      (const float*)d_in[7],  (const float*)d_in[8],  (const float*)d_in[9],
      (const float*)d_in[10], (const float*)d_in[11],
      (const float*)d_in[12], (const float*)d_in[13],
      (const float*)d_in[14], (const float*)d_in[15], (const float*)d_in[16],
      eidx, eidx + ETOT,
      (float*)d_out, K);
}